// Round 1
// baseline (789.198 us; speedup 1.0000x reference)
//
#include <hip/hip_runtime.h>

#define TS    256
#define ROWS  16
#define DIN   28

typedef _Float16 f16x4 __attribute__((ext_vector_type(4)));
typedef float    f32x4 __attribute__((ext_vector_type(4)));

#if __has_builtin(__builtin_amdgcn_rcpf)
#define RCPF(x) __builtin_amdgcn_rcpf(x)
#else
#define RCPF(x) (1.0f / (x))
#endif
#if __has_builtin(__builtin_amdgcn_exp2f)
#define EXP2F(x) __builtin_amdgcn_exp2f(x)
#else
#define EXP2F(x) exp2f(x)
#endif

__device__ __forceinline__ float sigm(float x) {
  return RCPF(1.0f + EXP2F(x * -1.44269504f));
}
__device__ __forceinline__ float tanhf_(float x) {
  // tanh(x) = 1 - 2/(exp2(x*2*log2e)+1); saturates correctly at +-inf
  return 1.0f - 2.0f * RCPF(1.0f + EXP2F(x * 2.885390082f));
}
__device__ __forceinline__ f16x4 cvt4(float a, float b, float c, float d) {
  f16x4 r; r[0] = (_Float16)a; r[1] = (_Float16)b; r[2] = (_Float16)c; r[3] = (_Float16)d;
  return r;
}
__device__ __forceinline__ f16x4 cvt4v(float4 v) { return cvt4(v.x, v.y, v.z, v.w); }

#define MFMA16(a, b, c) __builtin_amdgcn_mfma_f32_16x16x16f16((a), (b), (c), 0, 0, 0)

// One persistent kernel: 256 blocks x 16 batch rows; all 4 LSTM layers advance
// together inside the timestep loop. Weights held as fp16 MFMA B-fragments in
// VGPRs (~240 regs); h double-buffered in LDS (pitch 72 halves = 2-way-free
// bank pattern); one __syncthreads per layer-phase (4 per timestep).
__global__ __launch_bounds__(256, 1) void lstm4_fused(
    const float* __restrict__ x,
    const float* __restrict__ Wih0, const float* __restrict__ Whh0,
    const float* __restrict__ bih0, const float* __restrict__ bhh0,
    const float* __restrict__ Wih1, const float* __restrict__ Whh1,
    const float* __restrict__ bih1, const float* __restrict__ bhh1,
    const float* __restrict__ Wih2, const float* __restrict__ Whh2,
    const float* __restrict__ bih2, const float* __restrict__ bhh2,
    const float* __restrict__ Wih3, const float* __restrict__ Whh3,
    const float* __restrict__ bih3, const float* __restrict__ bhh3,
    const float* __restrict__ Wout, const float* __restrict__ bout,
    float* __restrict__ out)
{
  const int tid  = (int)threadIdx.x;
  const int lane = tid & 63;
  const int wv   = tid >> 6;   // wave 0..3 -> owns h-cols [16wv, 16wv+16)
  const int r    = lane & 15;  // A-row (batch row) / B-col (h col within tile)
  const int q    = lane >> 4;  // quarter-group -> k = 4q+i
  const int r0   = (int)blockIdx.x * ROWS;

  __shared__ _Float16 hsb[4][2][ROWS][72];  // [layer][buf][batch row][h col], padded pitch

  for (int i = tid; i < 4 * 2 * ROWS * 72; i += 256)
    (&hsb[0][0][0][0])[i] = (_Float16)0.0f;

  const float* WihA[4] = {Wih0, Wih1, Wih2, Wih3};
  const float* WhhA[4] = {Whh0, Whh1, Whh2, Whh3};
  const float* bihA[4] = {bih0, bih1, bih2, bih3};
  const float* bhhA[4] = {bhh0, bhh1, bhh2, bhh3};

  // B-fragments: lane holds W[col][4q+i+16s] (i.e. B[k][n] = W[n][k])
  f16x4 wx0[4][2];     // layer 0 input weights, K=32 (28 padded)
  f16x4 wxl[3][4][4];  // layers 1..3 input weights, K=64
  f16x4 whh[4][4][4];  // recurrent weights, K=64
  float bv[4][4];      // bias per [layer][gate] at this lane's col

#pragma unroll
  for (int nt = 0; nt < 4; ++nt) {   // gate: 0=i 1=f 2=g 3=o
    const int col = 64 * nt + 16 * wv + r;
    wx0[nt][0] = cvt4v(*(const float4*)&Wih0[col * DIN + 4 * q]);
    if (q < 3) wx0[nt][1] = cvt4v(*(const float4*)&Wih0[col * DIN + 16 + 4 * q]);
    else       wx0[nt][1] = cvt4(0.f, 0.f, 0.f, 0.f);  // k=28..31 zero pad
#pragma unroll
    for (int l = 1; l < 4; ++l)
#pragma unroll
      for (int s = 0; s < 4; ++s)
        wxl[l - 1][nt][s] = cvt4v(*(const float4*)&WihA[l][col * 64 + 16 * s + 4 * q]);
#pragma unroll
    for (int l = 0; l < 4; ++l) {
#pragma unroll
      for (int s = 0; s < 4; ++s)
        whh[l][nt][s] = cvt4v(*(const float4*)&WhhA[l][col * 64 + 16 * s + 4 * q]);
      bv[l][nt] = bihA[l][col] + bhhA[l][col];
    }
  }

  // x A-fragments straight from global: x[r0+r][t][4q+i(+16)], 16B aligned
  const float* xrow = x + (size_t)(r0 + r) * (TS * DIN);
  f16x4 xa0, xa1;
  {
    xa0 = cvt4v(*(const float4*)&xrow[4 * q]);
    if (q < 3) xa1 = cvt4v(*(const float4*)&xrow[16 + 4 * q]);
    else       xa1 = cvt4(0.f, 0.f, 0.f, 0.f);
  }

  f32x4 cst[4];
#pragma unroll
  for (int l = 0; l < 4; ++l) cst[l] = f32x4{0.f, 0.f, 0.f, 0.f};
  f32x4 hval = f32x4{0.f, 0.f, 0.f, 0.f};

  auto phase = [&](const int t, const int buf) {
    const int pbuf = buf ^ 1;
    // ---------- layer 0 ----------
    if (t > 0) {  // publish h3_{t-1} (computed in previous timestep's last phase)
#pragma unroll
      for (int j = 0; j < 4; ++j)
        hsb[3][pbuf][4 * q + j][16 * wv + r] = (_Float16)hval[j];
    }
    __syncthreads();
    {
      f32x4 acc[4];
#pragma unroll
      for (int nt = 0; nt < 4; ++nt)
        acc[nt] = f32x4{bv[0][nt], bv[0][nt], bv[0][nt], bv[0][nt]};
#pragma unroll
      for (int nt = 0; nt < 4; ++nt) acc[nt] = MFMA16(xa0, wx0[nt][0], acc[nt]);
#pragma unroll
      for (int nt = 0; nt < 4; ++nt) acc[nt] = MFMA16(xa1, wx0[nt][1], acc[nt]);
      if (t + 1 < TS) {  // prefetch next timestep's x (a full timestep of slack)
        const float4 v0 = *(const float4*)&xrow[(t + 1) * DIN + 4 * q];
        float4 v1 = make_float4(0.f, 0.f, 0.f, 0.f);
        if (q < 3) v1 = *(const float4*)&xrow[(t + 1) * DIN + 16 + 4 * q];
        xa0 = cvt4v(v0);
        xa1 = cvt4v(v1);
      }
#pragma unroll
      for (int s = 0; s < 4; ++s) {
        const f16x4 a = *(const f16x4*)&hsb[0][pbuf][r][16 * s + 4 * q];
#pragma unroll
        for (int nt = 0; nt < 4; ++nt) acc[nt] = MFMA16(a, whh[0][nt][s], acc[nt]);
      }
#pragma unroll
      for (int j = 0; j < 4; ++j) {
        const float ig = sigm(acc[0][j]);
        const float fg = sigm(acc[1][j]);
        const float gg = tanhf_(acc[2][j]);
        const float og = sigm(acc[3][j]);
        const float c  = fg * cst[0][j] + ig * gg;
        cst[0][j] = c;
        hval[j]   = og * tanhf_(c);
      }
    }
    // ---------- layers 1..3 ----------
#pragma unroll
    for (int l = 1; l < 4; ++l) {
#pragma unroll
      for (int j = 0; j < 4; ++j)  // publish h^{l-1}_t
        hsb[l - 1][buf][4 * q + j][16 * wv + r] = (_Float16)hval[j];
      __syncthreads();
      f32x4 acc[4];
#pragma unroll
      for (int nt = 0; nt < 4; ++nt)
        acc[nt] = f32x4{bv[l][nt], bv[l][nt], bv[l][nt], bv[l][nt]};
#pragma unroll
      for (int s = 0; s < 4; ++s) {  // input part: h^{l-1}_t
        const f16x4 a = *(const f16x4*)&hsb[l - 1][buf][r][16 * s + 4 * q];
#pragma unroll
        for (int nt = 0; nt < 4; ++nt) acc[nt] = MFMA16(a, wxl[l - 1][nt][s], acc[nt]);
      }
#pragma unroll
      for (int s = 0; s < 4; ++s) {  // recurrent part: h^l_{t-1}
        const f16x4 a = *(const f16x4*)&hsb[l][pbuf][r][16 * s + 4 * q];
#pragma unroll
        for (int nt = 0; nt < 4; ++nt) acc[nt] = MFMA16(a, whh[l][nt][s], acc[nt]);
      }
#pragma unroll
      for (int j = 0; j < 4; ++j) {
        const float ig = sigm(acc[0][j]);
        const float fg = sigm(acc[1][j]);
        const float gg = tanhf_(acc[2][j]);
        const float og = sigm(acc[3][j]);
        const float c  = fg * cst[l][j] + ig * gg;
        cst[l][j] = c;
        hval[j]   = og * tanhf_(c);
      }
    }
  };

  for (int t2 = 0; t2 < TS; t2 += 2) {  // unroll x2 so buf is compile-time
    phase(t2, 0);
    phase(t2 + 1, 1);
  }

  // epilogue: hval = h3_255; final linear [16 rows]x[10 out]
#pragma unroll
  for (int j = 0; j < 4; ++j)
    hsb[3][1][4 * q + j][16 * wv + r] = (_Float16)hval[j];
  __syncthreads();

  if (tid < 160) {
    const int rr = tid & 15;
    const int oc = tid >> 4;
    float a = bout[oc];
#pragma unroll 16
    for (int k = 0; k < 64; ++k)
      a += (float)hsb[3][1][rr][k] * Wout[oc * 64 + k];
    out[(size_t)(r0 + rr) * 10 + oc] = a;
  }
}

extern "C" void kernel_launch(void* const* d_in, const int* in_sizes, int n_in,
                              void* d_out, int out_size, void* d_ws, size_t ws_size,
                              hipStream_t stream) {
  (void)in_sizes; (void)n_in; (void)d_ws; (void)ws_size; (void)out_size;
  lstm4_fused<<<dim3(4096 / ROWS), dim3(256), 0, stream>>>(
      (const float*)d_in[0],
      (const float*)d_in[1],  (const float*)d_in[2],  (const float*)d_in[3],  (const float*)d_in[4],
      (const float*)d_in[5],  (const float*)d_in[6],  (const float*)d_in[7],  (const float*)d_in[8],
      (const float*)d_in[9],  (const float*)d_in[10], (const float*)d_in[11], (const float*)d_in[12],
      (const float*)d_in[13], (const float*)d_in[14], (const float*)d_in[15], (const float*)d_in[16],
      (const float*)d_in[17], (const float*)d_in[18],
      (float*)d_out);
}

// Round 2
// 505.648 us; speedup vs baseline: 1.5608x; 1.5608x over previous
//
#include <hip/hip_runtime.h>

#define TS    256
#define ROWS  16
#define DIN   28

typedef _Float16 f16x4 __attribute__((ext_vector_type(4)));
typedef float    f32x4 __attribute__((ext_vector_type(4)));

#if __has_builtin(__builtin_amdgcn_rcpf)
#define RCPF(x) __builtin_amdgcn_rcpf(x)
#else
#define RCPF(x) (1.0f / (x))
#endif
#if __has_builtin(__builtin_amdgcn_exp2f)
#define EXP2F(x) __builtin_amdgcn_exp2f(x)
#else
#define EXP2F(x) exp2f(x)
#endif

__device__ __forceinline__ float sigm(float x) {
  return RCPF(1.0f + EXP2F(x * -1.44269504f));
}
__device__ __forceinline__ float tanhf_(float x) {
  // tanh(x) = 1 - 2/(exp2(2x*log2e)+1); saturates correctly at +-inf
  return 1.0f - 2.0f * RCPF(1.0f + EXP2F(x * 2.885390082f));
}
__device__ __forceinline__ f16x4 cvt4(float a, float b, float c, float d) {
  f16x4 r; r[0] = (_Float16)a; r[1] = (_Float16)b; r[2] = (_Float16)c; r[3] = (_Float16)d;
  return r;
}
__device__ __forceinline__ f16x4 cvt4v(float4 v) { return cvt4(v.x, v.y, v.z, v.w); }

#define MFMA16(a, b, c) __builtin_amdgcn_mfma_f32_16x16x16f16((a), (b), (c), 0, 0, 0)

// Diagonal software pipeline: 1024-thread block = 4 layer-groups x 4 col-waves.
// At step s, layer-group l processes timestep t = s - l; all 4 layers run
// concurrently in different waves. Each wave holds ONE layer's weights
// (~68 VGPR) -> <=128 VGPR -> 4 waves/SIMD. h double-buffered in LDS by
// parity of the producer's t; one barrier per step (259 total).
__global__ __launch_bounds__(1024, 4) void lstm4_pipe(
    const float* __restrict__ x,
    const float* __restrict__ Wih0, const float* __restrict__ Whh0,
    const float* __restrict__ bih0, const float* __restrict__ bhh0,
    const float* __restrict__ Wih1, const float* __restrict__ Whh1,
    const float* __restrict__ bih1, const float* __restrict__ bhh1,
    const float* __restrict__ Wih2, const float* __restrict__ Whh2,
    const float* __restrict__ bih2, const float* __restrict__ bhh2,
    const float* __restrict__ Wih3, const float* __restrict__ Whh3,
    const float* __restrict__ bih3, const float* __restrict__ bhh3,
    const float* __restrict__ Wout, const float* __restrict__ bout,
    float* __restrict__ out)
{
  const int tid  = (int)threadIdx.x;
  const int lane = tid & 63;
  const int w    = tid >> 6;   // wave 0..15
  const int l    = w >> 2;     // layer group 0..3
  const int wv   = w & 3;      // col tile within layer -> h cols [16wv,16wv+16)
  const int r    = lane & 15;  // A-row (batch row) / B-col (h col within tile)
  const int q    = lane >> 4;  // quarter-group -> k = 4q+i
  const int r0   = (int)blockIdx.x * ROWS;

  __shared__ _Float16 hbuf[4][2][ROWS][72];  // [layer][parity][row][col], padded pitch

  for (int i = tid; i < 4 * 2 * ROWS * 72; i += 1024)
    (&hbuf[0][0][0][0])[i] = (_Float16)0.0f;

  const float* Wih = (l == 0) ? Wih0 : (l == 1) ? Wih1 : (l == 2) ? Wih2 : Wih3;
  const float* Whh = (l == 0) ? Whh0 : (l == 1) ? Whh1 : (l == 2) ? Whh2 : Whh3;
  const float* bih = (l == 0) ? bih0 : (l == 1) ? bih1 : (l == 2) ? bih2 : bih3;
  const float* bhh = (l == 0) ? bhh0 : (l == 1) ? bhh1 : (l == 2) ? bhh2 : bhh3;

  // B-fragments for THIS wave's layer only: lane holds W[col][4q+i+16s]
  f16x4 wx[4][4];  // input weights (layer 0 uses only s=0,1 with K=28 zero-padded)
  f16x4 wh[4][4];  // recurrent weights, K=64
  float bv[4];     // bias per gate at this lane's col

#pragma unroll
  for (int nt = 0; nt < 4; ++nt) {   // gate: 0=i 1=f 2=g 3=o
    const int col = 64 * nt + 16 * wv + r;
    if (l == 0) {
      wx[nt][0] = cvt4v(*(const float4*)&Wih[col * DIN + 4 * q]);
      wx[nt][1] = (q < 3) ? cvt4v(*(const float4*)&Wih[col * DIN + 16 + 4 * q])
                          : cvt4(0.f, 0.f, 0.f, 0.f);
      wx[nt][2] = cvt4(0.f, 0.f, 0.f, 0.f);
      wx[nt][3] = cvt4(0.f, 0.f, 0.f, 0.f);
    } else {
#pragma unroll
      for (int s = 0; s < 4; ++s)
        wx[nt][s] = cvt4v(*(const float4*)&Wih[col * 64 + 16 * s + 4 * q]);
    }
#pragma unroll
    for (int s = 0; s < 4; ++s)
      wh[nt][s] = cvt4v(*(const float4*)&Whh[col * 64 + 16 * s + 4 * q]);
    bv[nt] = bih[col] + bhh[col];
  }

  // x A-fragments straight from global (layer-0 group only): x[r0+r][t][4q+i(+16)]
  const float* xrow = x + (size_t)(r0 + r) * (TS * DIN);
  f16x4 xa0 = cvt4(0.f, 0.f, 0.f, 0.f), xa1 = cvt4(0.f, 0.f, 0.f, 0.f);
  if (l == 0) {
    xa0 = cvt4v(*(const float4*)&xrow[4 * q]);
    if (q < 3) xa1 = cvt4v(*(const float4*)&xrow[16 + 4 * q]);
  }

  f32x4 cst = f32x4{0.f, 0.f, 0.f, 0.f};  // c state for THIS wave's layer

  for (int s = 0; s < TS + 3; ++s) {
    __syncthreads();
    const int t = s - l;
    if (t < 0 || t >= TS) continue;  // every iteration has exactly one barrier
    const int pi = t & 1;            // parity this group writes (and reads from l-1)

    f32x4 acc[4];
#pragma unroll
    for (int nt = 0; nt < 4; ++nt)
      acc[nt] = f32x4{bv[nt], bv[nt], bv[nt], bv[nt]};

    if (l == 0) {
#pragma unroll
      for (int nt = 0; nt < 4; ++nt) acc[nt] = MFMA16(xa0, wx[nt][0], acc[nt]);
#pragma unroll
      for (int nt = 0; nt < 4; ++nt) acc[nt] = MFMA16(xa1, wx[nt][1], acc[nt]);
      if (t + 1 < TS) {  // prefetch next timestep's x (a full step of slack)
        const float4 v0 = *(const float4*)&xrow[(t + 1) * DIN + 4 * q];
        float4 v1 = make_float4(0.f, 0.f, 0.f, 0.f);
        if (q < 3) v1 = *(const float4*)&xrow[(t + 1) * DIN + 16 + 4 * q];
        xa0 = cvt4v(v0);
        xa1 = cvt4v(v1);
      }
    } else {
      // input part: h^{l-1}_t, written by group l-1 last step at parity t&1
      const _Float16* pin = &hbuf[l - 1][pi][r][4 * q];
#pragma unroll
      for (int s2 = 0; s2 < 4; ++s2) {
        const f16x4 a = *(const f16x4*)&pin[16 * s2];
#pragma unroll
        for (int nt = 0; nt < 4; ++nt) acc[nt] = MFMA16(a, wx[nt][s2], acc[nt]);
      }
    }
    {
      // recurrent part: h^l_{t-1}, written by this group last step at parity (t-1)&1
      const _Float16* prc = &hbuf[l][pi ^ 1][r][4 * q];
#pragma unroll
      for (int s2 = 0; s2 < 4; ++s2) {
        const f16x4 a = *(const f16x4*)&prc[16 * s2];
#pragma unroll
        for (int nt = 0; nt < 4; ++nt) acc[nt] = MFMA16(a, wh[nt][s2], acc[nt]);
      }
    }

    _Float16* pw = &hbuf[l][pi][4 * q][16 * wv + r];
#pragma unroll
    for (int j = 0; j < 4; ++j) {
      const float ig = sigm(acc[0][j]);
      const float fg = sigm(acc[1][j]);
      const float gg = tanhf_(acc[2][j]);
      const float og = sigm(acc[3][j]);
      const float c  = fg * cst[j] + ig * gg;
      cst[j] = c;
      pw[j * 72] = (_Float16)(og * tanhf_(c));
    }
  }

  __syncthreads();

  // epilogue: h3_{255} is in hbuf[3][255&1 = 1]; final linear [16 rows]x[10 out]
  if (tid < 160) {
    const int rr = tid & 15;
    const int oc = tid >> 4;
    float a = bout[oc];
#pragma unroll 16
    for (int k = 0; k < 64; ++k)
      a += (float)hbuf[3][1][rr][k] * Wout[oc * 64 + k];
    out[(size_t)(r0 + rr) * 10 + oc] = a;
  }
}

extern "C" void kernel_launch(void* const* d_in, const int* in_sizes, int n_in,
                              void* d_out, int out_size, void* d_ws, size_t ws_size,
                              hipStream_t stream) {
  (void)in_sizes; (void)n_in; (void)d_ws; (void)ws_size; (void)out_size;
  lstm4_pipe<<<dim3(4096 / ROWS), dim3(1024), 0, stream>>>(
      (const float*)d_in[0],
      (const float*)d_in[1],  (const float*)d_in[2],  (const float*)d_in[3],  (const float*)d_in[4],
      (const float*)d_in[5],  (const float*)d_in[6],  (const float*)d_in[7],  (const float*)d_in[8],
      (const float*)d_in[9],  (const float*)d_in[10], (const float*)d_in[11], (const float*)d_in[12],
      (const float*)d_in[13], (const float*)d_in[14], (const float*)d_in[15], (const float*)d_in[16],
      (const float*)d_in[17], (const float*)d_in[18],
      (float*)d_out);
}